// Round 2
// baseline (105.432 us; speedup 1.0000x reference)
//
#include <hip/hip_runtime.h>
#include <math.h>

#define NATOMS 21
#define DESC 210
#define DPAD 216
#define NTRAIN 4096
#define NM 128

#define SIGC 10.0f
#define CC 0.0f
#define STDC 1.0f
// q = sqrt(5)/sig
#define QS 0.22360679774997896f
// 5/(3*sig^2)
#define KE 0.016666666666666666f

__device__ __forceinline__ void pair_ij(int p, int& i, int& j) {
    int ii = (int)((1.0f + sqrtf(1.0f + 8.0f * (float)p)) * 0.5f);
    while (ii * (ii - 1) / 2 > p) --ii;
    while ((ii + 1) * ii / 2 <= p) ++ii;
    i = ii;
    j = p - ii * (ii - 1) / 2;
}

// A: per-molecule pair descriptors. aT[d*128+m] = q/r_d (zero-padded to DPAD rows)
__global__ __launch_bounds__(256) void k_desc(const float* __restrict__ Rs,
                                              float* __restrict__ aT,
                                              float* __restrict__ asq) {
    const int m = blockIdx.x;
    __shared__ float R[NATOMS * 3];
    __shared__ float red[4];
    const int tid = threadIdx.x;
    if (tid < NATOMS * 3) R[tid] = Rs[m * NATOMS * 3 + tid];
    __syncthreads();
    float a2 = 0.0f;
    if (tid < DPAD) {
        float a = 0.0f;
        if (tid < DESC) {
            int i, j;
            pair_ij(tid, i, j);
            const float dx = R[i * 3 + 0] - R[j * 3 + 0];
            const float dy = R[i * 3 + 1] - R[j * 3 + 1];
            const float dz = R[i * 3 + 2] - R[j * 3 + 2];
            const float r2 = dx * dx + dy * dy + dz * dz;
            a = QS / sqrtf(r2);
        }
        aT[tid * NM + m] = a;
        a2 = a * a;
    }
    #pragma unroll
    for (int off = 32; off > 0; off >>= 1) a2 += __shfl_down(a2, off, 64);
    if ((tid & 63) == 0) red[tid >> 6] = a2;
    __syncthreads();
    if (tid == 0) asq[m] = red[0] + red[1] + red[2] + red[3];
}

// B: build interleaved bj[d][t] = {q*xs_train[t][d], Jx[t][d]} (float2), d zero-padded
__global__ __launch_bounds__(256) void k_interleave(const float* __restrict__ xs_train,
                                                    const float* __restrict__ Jx,
                                                    float2* __restrict__ bj2) {
    const int t = blockIdx.x;
    const int d = threadIdx.x;
    if (d < DPAD) {
        float b = 0.0f, jv = 0.0f;
        if (d < DESC) {
            b = QS * xs_train[t * DESC + d];
            jv = Jx[t * DESC + d];
        }
        bj2[d * NTRAIN + t] = make_float2(b, jv);
    }
}

// C: pass 1 — per (m,t): dist, dot, weights w1/w2; accumulate Es and S1.
// 8-deep software pipeline over d; a-slice staged in LDS.
__global__ __launch_bounds__(256) void k_pass1(const float2* __restrict__ bj2,
                                               const float* __restrict__ aT,
                                               const float* __restrict__ asq,
                                               float* __restrict__ w1T,
                                               float* __restrict__ w2T,
                                               float* __restrict__ EsAcc,
                                               float* __restrict__ S1) {
    const int t = blockIdx.x * 256 + threadIdx.x;
    const int m0 = blockIdx.y * 8;
    __shared__ float aS[DPAD * 8];  // [d][mi]
    for (int idx = threadIdx.x; idx < DPAD * 8; idx += 256) {
        const int d = idx >> 3;
        const int mi = idx & 7;
        aS[idx] = aT[d * NM + m0 + mi];
    }
    __syncthreads();

    float P[8], Q[8];
    #pragma unroll
    for (int mi = 0; mi < 8; ++mi) { P[mi] = 0.0f; Q[mi] = 0.0f; }
    float bsq = 0.0f, cj = 0.0f;

    float2 cur[8], nxt[8];
    #pragma unroll
    for (int u = 0; u < 8; ++u) cur[u] = bj2[u * NTRAIN + t];

    for (int d0 = 0; d0 < DPAD; d0 += 8) {
        const int dn = (d0 + 8 < DPAD) ? (d0 + 8) : 0;
        #pragma unroll
        for (int u = 0; u < 8; ++u) nxt[u] = bj2[(dn + u) * NTRAIN + t];
        #pragma unroll
        for (int u = 0; u < 8; ++u) {
            const float bv = cur[u].x;
            const float jv = cur[u].y;
            bsq = fmaf(bv, bv, bsq);
            cj = fmaf(bv, jv, cj);
            const float4 a0 = *reinterpret_cast<const float4*>(&aS[(d0 + u) * 8]);
            const float4 a1 = *reinterpret_cast<const float4*>(&aS[(d0 + u) * 8 + 4]);
            P[0] = fmaf(a0.x, bv, P[0]); P[1] = fmaf(a0.y, bv, P[1]);
            P[2] = fmaf(a0.z, bv, P[2]); P[3] = fmaf(a0.w, bv, P[3]);
            P[4] = fmaf(a1.x, bv, P[4]); P[5] = fmaf(a1.y, bv, P[5]);
            P[6] = fmaf(a1.z, bv, P[6]); P[7] = fmaf(a1.w, bv, P[7]);
            Q[0] = fmaf(a0.x, jv, Q[0]); Q[1] = fmaf(a0.y, jv, Q[1]);
            Q[2] = fmaf(a0.z, jv, Q[2]); Q[3] = fmaf(a0.w, jv, Q[3]);
            Q[4] = fmaf(a1.x, jv, Q[4]); Q[5] = fmaf(a1.y, jv, Q[5]);
            Q[6] = fmaf(a1.z, jv, Q[6]); Q[7] = fmaf(a1.w, jv, Q[7]);
        }
        #pragma unroll
        for (int u = 0; u < 8; ++u) cur[u] = nxt[u];
    }

    float esv[8], s1v[8], w1o[8], w2o[8];
    #pragma unroll
    for (int mi = 0; mi < 8; ++mi) {
        float dist2 = asq[m0 + mi] + bsq - 2.0f * P[mi];
        dist2 = fmaxf(dist2, 0.0f);
        const float x = sqrtf(dist2);
        const float e = KE * expf(-x);
        const float w2v = e * (1.0f + x);
        const float dotv = Q[mi] - cj;
        const float w1v = e * dotv;
        w1o[mi] = w1v;
        w2o[mi] = w2v;
        esv[mi] = w2v * dotv;
        s1v[mi] = w1v;
    }
    {
        float4 v;
        v.x = w1o[0]; v.y = w1o[1]; v.z = w1o[2]; v.w = w1o[3];
        *reinterpret_cast<float4*>(w1T + t * NM + m0) = v;
        v.x = w1o[4]; v.y = w1o[5]; v.z = w1o[6]; v.w = w1o[7];
        *reinterpret_cast<float4*>(w1T + t * NM + m0 + 4) = v;
        v.x = w2o[0]; v.y = w2o[1]; v.z = w2o[2]; v.w = w2o[3];
        *reinterpret_cast<float4*>(w2T + t * NM + m0) = v;
        v.x = w2o[4]; v.y = w2o[5]; v.z = w2o[6]; v.w = w2o[7];
        *reinterpret_cast<float4*>(w2T + t * NM + m0 + 4) = v;
    }
    #pragma unroll
    for (int off = 32; off > 0; off >>= 1) {
        #pragma unroll
        for (int mi = 0; mi < 8; ++mi) {
            esv[mi] += __shfl_down(esv[mi], off, 64);
            s1v[mi] += __shfl_down(s1v[mi], off, 64);
        }
    }
    if ((threadIdx.x & 63) == 0) {
        #pragma unroll
        for (int mi = 0; mi < 8; ++mi) {
            atomicAdd(&EsAcc[m0 + mi], esv[mi]);
            atomicAdd(&S1[m0 + mi], s1v[mi]);
        }
    }
}

// D: pass 2 — F1acc[m][d] += sum_t w1[t][m]*q*xs_train[t][d];
//            F2acc[m][d] += sum_t w2[t][m]*Jx[t][d]
// w staged in LDS (broadcast reads); t-chunk 128 for occupancy.
#define TC2 128
__global__ __launch_bounds__(256) void k_pass2(const float* __restrict__ xs_train,
                                               const float* __restrict__ Jx,
                                               const float* __restrict__ w1T,
                                               const float* __restrict__ w2T,
                                               float* __restrict__ F1acc,
                                               float* __restrict__ F2acc) {
    const int d = threadIdx.x;
    const int t0 = blockIdx.x * TC2;
    const int m0 = blockIdx.y * 8;
    __shared__ float w1S[TC2 * 8];  // [tt][mi]
    __shared__ float w2S[TC2 * 8];
    for (int idx = threadIdx.x; idx < TC2 * 8; idx += 256) {
        const int tt = idx >> 3;
        const int mi = idx & 7;
        w1S[idx] = w1T[(t0 + tt) * NM + m0 + mi];
        w2S[idx] = w2T[(t0 + tt) * NM + m0 + mi];
    }
    __syncthreads();
    if (d >= DESC) return;

    float G1[8], G2[8];
    #pragma unroll
    for (int mi = 0; mi < 8; ++mi) { G1[mi] = 0.0f; G2[mi] = 0.0f; }

    for (int tc = 0; tc < TC2; tc += 8) {
        float xsv[8], jxv[8];
        #pragma unroll
        for (int u = 0; u < 8; ++u) {
            const int t = t0 + tc + u;
            xsv[u] = xs_train[t * DESC + d];
            jxv[u] = Jx[t * DESC + d];
        }
        #pragma unroll
        for (int u = 0; u < 8; ++u) {
            const float bv = QS * xsv[u];
            const float jv = jxv[u];
            const float4 wa = *reinterpret_cast<const float4*>(&w1S[(tc + u) * 8]);
            const float4 wb = *reinterpret_cast<const float4*>(&w1S[(tc + u) * 8 + 4]);
            const float4 va = *reinterpret_cast<const float4*>(&w2S[(tc + u) * 8]);
            const float4 vb = *reinterpret_cast<const float4*>(&w2S[(tc + u) * 8 + 4]);
            G1[0] = fmaf(wa.x, bv, G1[0]); G1[1] = fmaf(wa.y, bv, G1[1]);
            G1[2] = fmaf(wa.z, bv, G1[2]); G1[3] = fmaf(wa.w, bv, G1[3]);
            G1[4] = fmaf(wb.x, bv, G1[4]); G1[5] = fmaf(wb.y, bv, G1[5]);
            G1[6] = fmaf(wb.z, bv, G1[6]); G1[7] = fmaf(wb.w, bv, G1[7]);
            G2[0] = fmaf(va.x, jv, G2[0]); G2[1] = fmaf(va.y, jv, G2[1]);
            G2[2] = fmaf(va.z, jv, G2[2]); G2[3] = fmaf(va.w, jv, G2[3]);
            G2[4] = fmaf(vb.x, jv, G2[4]); G2[5] = fmaf(vb.y, jv, G2[5]);
            G2[6] = fmaf(vb.z, jv, G2[6]); G2[7] = fmaf(vb.w, jv, G2[7]);
        }
    }
    #pragma unroll
    for (int mi = 0; mi < 8; ++mi) {
        atomicAdd(&F1acc[(m0 + mi) * DESC + d], G1[mi]);
        atomicAdd(&F2acc[(m0 + mi) * DESC + d], G2[mi]);
    }
}

// E: final assembly — coef, force scatter, Es
__global__ __launch_bounds__(256) void k_final(const float* __restrict__ Rs,
                                               const float* __restrict__ aT,
                                               const float* __restrict__ S1,
                                               const float* __restrict__ EsAcc,
                                               const float* __restrict__ F1acc,
                                               const float* __restrict__ F2acc,
                                               float* __restrict__ out) {
    const int m = blockIdx.x;
    __shared__ float R[NATOMS * 3];
    __shared__ float FsL[NATOMS * 3];
    const int tid = threadIdx.x;
    if (tid < NATOMS * 3) {
        R[tid] = Rs[m * NATOMS * 3 + tid];
        FsL[tid] = 0.0f;
    }
    __syncthreads();
    if (tid < DESC) {
        int i, j;
        pair_ij(tid, i, j);
        const float dx = R[i * 3 + 0] - R[j * 3 + 0];
        const float dy = R[i * 3 + 1] - R[j * 3 + 1];
        const float dz = R[i * 3 + 2] - R[j * 3 + 2];
        const float r2 = dx * dx + dy * dy + dz * dz;
        const float rinv = 1.0f / sqrtf(r2);
        const float a = aT[tid * NM + m];  // q/r
        const float F1 = a * S1[m] - F1acc[m * DESC + tid];
        const float Fx = (F1 - F2acc[m * DESC + tid]) * STDC;
        const float coef = Fx * (rinv * rinv * rinv);
        atomicAdd(&FsL[j * 3 + 0], coef * dx);
        atomicAdd(&FsL[j * 3 + 1], coef * dy);
        atomicAdd(&FsL[j * 3 + 2], coef * dz);
        atomicAdd(&FsL[i * 3 + 0], -coef * dx);
        atomicAdd(&FsL[i * 3 + 1], -coef * dy);
        atomicAdd(&FsL[i * 3 + 2], -coef * dz);
    }
    __syncthreads();
    if (tid < NATOMS * 3) out[NM + m * NATOMS * 3 + tid] = FsL[tid];
    if (tid == 0) out[m] = CC + (EsAcc[m] / QS) * STDC;
}

extern "C" void kernel_launch(void* const* d_in, const int* in_sizes, int n_in,
                              void* d_out, int out_size, void* d_ws, size_t ws_size,
                              hipStream_t stream) {
    const float* Rs = (const float*)d_in[0];
    const float* xs_train = (const float*)d_in[1];
    const float* Jx = (const float*)d_in[2];
    float* out = (float*)d_out;
    float* ws = (float*)d_ws;

    float* F1acc = ws;                        // 26880
    float* F2acc = ws + 26880;                // 26880
    float* EsAcc = ws + 53760;                // 128
    float* S1 = ws + 53888;                   // 128
    float* aT = ws + 54016;                   // 216*128 = 27648
    float* asq = ws + 81664;                  // 128
    float2* bj2 = (float2*)(ws + 81792);      // 216*4096*2 = 1769472 floats
    float* w1T = ws + 1851264;                // 524288
    float* w2T = ws + 2375552;                // 524288 -> total 2899840 floats (~11.6 MB)

    hipMemsetAsync(ws, 0, (size_t)54016 * sizeof(float), stream);

    k_desc<<<NM, 256, 0, stream>>>(Rs, aT, asq);
    k_interleave<<<NTRAIN, 256, 0, stream>>>(xs_train, Jx, bj2);
    k_pass1<<<dim3(NTRAIN / 256, NM / 8), 256, 0, stream>>>(bj2, aT, asq, w1T, w2T,
                                                            EsAcc, S1);
    k_pass2<<<dim3(NTRAIN / TC2, NM / 8), 256, 0, stream>>>(xs_train, Jx, w1T, w2T,
                                                            F1acc, F2acc);
    k_final<<<NM, 256, 0, stream>>>(Rs, aT, S1, EsAcc, F1acc, F2acc, out);
}

// Round 3
// 100.710 us; speedup vs baseline: 1.0469x; 1.0469x over previous
//
#include <hip/hip_runtime.h>
#include <math.h>

#define NATOMS 21
#define DESC 210
#define DPAD 224          // padded descriptor count (multiple of 32)
#define P4 112            // DPAD/2 — float4-packed descriptor pairs
#define NTRAIN 4096
#define NM 128

#define CC 0.0f
#define STDC 1.0f
// q = sqrt(5)/sig
#define QS 0.22360679774997896f
// 5/(3*sig^2)
#define KE 0.016666666666666666f

__device__ __forceinline__ void pair_ij(int p, int& i, int& j) {
    int ii = (int)((1.0f + sqrtf(1.0f + 8.0f * (float)p)) * 0.5f);
    while (ii * (ii - 1) / 2 > p) --ii;
    while ((ii + 1) * ii / 2 <= p) ++ii;
    i = ii;
    j = p - ii * (ii - 1) / 2;
}

// prep: blocks [0,448) do the xs/Jx transpose+pack; blocks [448,576) do per-molecule descriptors.
// bjq[p][t] = {q*xs[t][2p], Jx[t][2p], q*xs[t][2p+1], Jx[t][2p+1]}, zero-padded for d>=210.
__global__ __launch_bounds__(256, 2) void k_prep(const float* __restrict__ Rs,
                                                 const float* __restrict__ xs_train,
                                                 const float* __restrict__ Jx,
                                                 float4* __restrict__ bjq,
                                                 float* __restrict__ aT,
                                                 float* __restrict__ asq) {
    __shared__ float smem[2 * 32 * 65 + 8];
    const int tid = threadIdx.x;
    const int bid = blockIdx.x;
    if (bid < 448) {
        float* ldsX = smem;
        float* ldsJ = smem + 32 * 65;
        const int bx = bid & 63;        // t tile
        const int by = bid >> 6;        // d tile (0..6)
        const int t0 = bx * 64;
        const int d0 = by * 32;
        #pragma unroll
        for (int k = 0; k < 8; ++k) {
            const int idx = tid + k * 256;        // 64t x 32d
            const int tt = idx >> 5;
            const int dd = idx & 31;
            const int d = d0 + dd;
            float xv = 0.0f, jv = 0.0f;
            if (d < DESC) {
                xv = QS * xs_train[(t0 + tt) * DESC + d];
                jv = Jx[(t0 + tt) * DESC + d];
            }
            ldsX[dd * 65 + tt] = xv;
            ldsJ[dd * 65 + tt] = jv;
        }
        __syncthreads();
        #pragma unroll
        for (int k = 0; k < 4; ++k) {
            const int idx = tid + k * 256;        // 16p x 64t
            const int pp = idx >> 6;
            const int tt = idx & 63;
            float4 v;
            v.x = ldsX[(2 * pp) * 65 + tt];
            v.y = ldsJ[(2 * pp) * 65 + tt];
            v.z = ldsX[(2 * pp + 1) * 65 + tt];
            v.w = ldsJ[(2 * pp + 1) * 65 + tt];
            bjq[(by * 16 + pp) * NTRAIN + t0 + tt] = v;
        }
    } else {
        const int m = bid - 448;
        float* R = smem;
        float* red = smem + 64;
        if (tid < NATOMS * 3) R[tid] = Rs[m * NATOMS * 3 + tid];
        __syncthreads();
        float a2 = 0.0f;
        if (tid < DPAD) {
            float a = 0.0f;
            if (tid < DESC) {
                int i, j;
                pair_ij(tid, i, j);
                const float dx = R[i * 3 + 0] - R[j * 3 + 0];
                const float dy = R[i * 3 + 1] - R[j * 3 + 1];
                const float dz = R[i * 3 + 2] - R[j * 3 + 2];
                a = QS / sqrtf(dx * dx + dy * dy + dz * dz);
            }
            aT[tid * NM + m] = a;
            a2 = a * a;
        }
        #pragma unroll
        for (int off = 32; off > 0; off >>= 1) a2 += __shfl_down(a2, off, 64);
        if ((tid & 63) == 0) red[tid >> 6] = a2;
        __syncthreads();
        if (tid == 0) asq[m] = red[0] + red[1] + red[2] + red[3];
    }
}

// pass 1: per (m,t) distance/dot/weights; Es and S1 reductions.
// lane = t; 8 molecules per block; K-loop over 112 float4-packed descriptor pairs,
// depth-1 prefetch of 8 float4 (keeps 8 16B loads in flight).
__global__ __launch_bounds__(256, 1) void k_pass1(const float4* __restrict__ bjq,
                                                  const float* __restrict__ aT,
                                                  const float* __restrict__ asq,
                                                  float* __restrict__ w1Tm,
                                                  float* __restrict__ w2Tm,
                                                  float* __restrict__ EsAcc,
                                                  float* __restrict__ S1) {
    const int t = blockIdx.x * 256 + threadIdx.x;
    const int m0 = blockIdx.y * 8;
    __shared__ __align__(16) float aS[DPAD * 8];  // [d][mi]
    #pragma unroll
    for (int k = 0; k < 7; ++k) {
        const int idx = threadIdx.x + k * 256;
        const int d = idx >> 3;
        const int mi = idx & 7;
        aS[idx] = aT[d * NM + m0 + mi];
    }
    __syncthreads();

    float P[8], Q[8];
    #pragma unroll
    for (int mi = 0; mi < 8; ++mi) { P[mi] = 0.0f; Q[mi] = 0.0f; }
    float bsq = 0.0f, cj = 0.0f;

    float4 cur[8], nxt[8];
    #pragma unroll
    for (int u = 0; u < 8; ++u) cur[u] = bjq[u * NTRAIN + t];

    for (int p0 = 0; p0 < P4; p0 += 8) {
        const int pn = (p0 + 8 < P4) ? (p0 + 8) : 0;
        #pragma unroll
        for (int u = 0; u < 8; ++u) nxt[u] = bjq[(pn + u) * NTRAIN + t];
        #pragma unroll
        for (int u = 0; u < 8; ++u) {
            const float b0 = cur[u].x, j0 = cur[u].y;
            const float b1 = cur[u].z, j1 = cur[u].w;
            bsq = fmaf(b0, b0, bsq); bsq = fmaf(b1, b1, bsq);
            cj = fmaf(b0, j0, cj);   cj = fmaf(b1, j1, cj);
            const float4 a0 = *reinterpret_cast<const float4*>(&aS[(p0 + u) * 16]);
            const float4 a1 = *reinterpret_cast<const float4*>(&aS[(p0 + u) * 16 + 4]);
            const float4 a2 = *reinterpret_cast<const float4*>(&aS[(p0 + u) * 16 + 8]);
            const float4 a3 = *reinterpret_cast<const float4*>(&aS[(p0 + u) * 16 + 12]);
            P[0] = fmaf(a0.x, b0, P[0]); P[1] = fmaf(a0.y, b0, P[1]);
            P[2] = fmaf(a0.z, b0, P[2]); P[3] = fmaf(a0.w, b0, P[3]);
            P[4] = fmaf(a1.x, b0, P[4]); P[5] = fmaf(a1.y, b0, P[5]);
            P[6] = fmaf(a1.z, b0, P[6]); P[7] = fmaf(a1.w, b0, P[7]);
            Q[0] = fmaf(a0.x, j0, Q[0]); Q[1] = fmaf(a0.y, j0, Q[1]);
            Q[2] = fmaf(a0.z, j0, Q[2]); Q[3] = fmaf(a0.w, j0, Q[3]);
            Q[4] = fmaf(a1.x, j0, Q[4]); Q[5] = fmaf(a1.y, j0, Q[5]);
            Q[6] = fmaf(a1.z, j0, Q[6]); Q[7] = fmaf(a1.w, j0, Q[7]);
            P[0] = fmaf(a2.x, b1, P[0]); P[1] = fmaf(a2.y, b1, P[1]);
            P[2] = fmaf(a2.z, b1, P[2]); P[3] = fmaf(a2.w, b1, P[3]);
            P[4] = fmaf(a3.x, b1, P[4]); P[5] = fmaf(a3.y, b1, P[5]);
            P[6] = fmaf(a3.z, b1, P[6]); P[7] = fmaf(a3.w, b1, P[7]);
            Q[0] = fmaf(a2.x, j1, Q[0]); Q[1] = fmaf(a2.y, j1, Q[1]);
            Q[2] = fmaf(a2.z, j1, Q[2]); Q[3] = fmaf(a2.w, j1, Q[3]);
            Q[4] = fmaf(a3.x, j1, Q[4]); Q[5] = fmaf(a3.y, j1, Q[5]);
            Q[6] = fmaf(a3.z, j1, Q[6]); Q[7] = fmaf(a3.w, j1, Q[7]);
        }
        #pragma unroll
        for (int u = 0; u < 8; ++u) cur[u] = nxt[u];
    }

    float esv[8], s1v[8];
    #pragma unroll
    for (int mi = 0; mi < 8; ++mi) {
        float dist2 = asq[m0 + mi] + bsq - 2.0f * P[mi];
        dist2 = fmaxf(dist2, 0.0f);
        const float x = sqrtf(dist2);
        const float e = KE * expf(-x);
        const float dotv = Q[mi] - cj;
        const float w1v = e * dotv;
        const float w2v = e * (1.0f + x);
        w1Tm[(m0 + mi) * NTRAIN + t] = w1v;
        w2Tm[(m0 + mi) * NTRAIN + t] = w2v;
        esv[mi] = w2v * dotv;
        s1v[mi] = w1v;
    }
    #pragma unroll
    for (int off = 32; off > 0; off >>= 1) {
        #pragma unroll
        for (int mi = 0; mi < 8; ++mi) {
            esv[mi] += __shfl_down(esv[mi], off, 64);
            s1v[mi] += __shfl_down(s1v[mi], off, 64);
        }
    }
    if ((threadIdx.x & 63) == 0) {
        #pragma unroll
        for (int mi = 0; mi < 8; ++mi) {
            atomicAdd(&EsAcc[m0 + mi], esv[mi]);
            atomicAdd(&S1[m0 + mi], s1v[mi]);
        }
    }
}

// pass 2: F1acc[m][d] += sum_t w1[m][t]*b[t][d]; F2acc[m][d] += sum_t w2[m][t]*Jx[t][d]
#define TC2 128
__global__ __launch_bounds__(256, 2) void k_pass2(const float* __restrict__ xs_train,
                                                  const float* __restrict__ Jx,
                                                  const float* __restrict__ w1Tm,
                                                  const float* __restrict__ w2Tm,
                                                  float* __restrict__ F1acc,
                                                  float* __restrict__ F2acc) {
    const int d = threadIdx.x;
    const int t0 = blockIdx.x * TC2;
    const int m0 = blockIdx.y * 8;
    __shared__ __align__(16) float w1S[TC2 * 8];  // [tt][mi]
    __shared__ __align__(16) float w2S[TC2 * 8];
    #pragma unroll
    for (int k = 0; k < 4; ++k) {
        const int idx = threadIdx.x + k * 256;
        const int mi = idx >> 7;
        const int tt = idx & 127;
        w1S[tt * 8 + mi] = w1Tm[(m0 + mi) * NTRAIN + t0 + tt];
        w2S[tt * 8 + mi] = w2Tm[(m0 + mi) * NTRAIN + t0 + tt];
    }
    __syncthreads();
    if (d >= DESC) return;

    float G1[8], G2[8];
    #pragma unroll
    for (int mi = 0; mi < 8; ++mi) { G1[mi] = 0.0f; G2[mi] = 0.0f; }

    float xc[8], jc[8], xn[8], jn[8];
    #pragma unroll
    for (int u = 0; u < 8; ++u) {
        xc[u] = xs_train[(t0 + u) * DESC + d];
        jc[u] = Jx[(t0 + u) * DESC + d];
    }
    for (int tc = 0; tc < TC2; tc += 8) {
        const int tn = (tc + 8 < TC2) ? (tc + 8) : 0;
        #pragma unroll
        for (int u = 0; u < 8; ++u) {
            xn[u] = xs_train[(t0 + tn + u) * DESC + d];
            jn[u] = Jx[(t0 + tn + u) * DESC + d];
        }
        #pragma unroll
        for (int u = 0; u < 8; ++u) {
            const float bv = QS * xc[u];
            const float jv = jc[u];
            const float4 wa = *reinterpret_cast<const float4*>(&w1S[(tc + u) * 8]);
            const float4 wb = *reinterpret_cast<const float4*>(&w1S[(tc + u) * 8 + 4]);
            const float4 va = *reinterpret_cast<const float4*>(&w2S[(tc + u) * 8]);
            const float4 vb = *reinterpret_cast<const float4*>(&w2S[(tc + u) * 8 + 4]);
            G1[0] = fmaf(wa.x, bv, G1[0]); G1[1] = fmaf(wa.y, bv, G1[1]);
            G1[2] = fmaf(wa.z, bv, G1[2]); G1[3] = fmaf(wa.w, bv, G1[3]);
            G1[4] = fmaf(wb.x, bv, G1[4]); G1[5] = fmaf(wb.y, bv, G1[5]);
            G1[6] = fmaf(wb.z, bv, G1[6]); G1[7] = fmaf(wb.w, bv, G1[7]);
            G2[0] = fmaf(va.x, jv, G2[0]); G2[1] = fmaf(va.y, jv, G2[1]);
            G2[2] = fmaf(va.z, jv, G2[2]); G2[3] = fmaf(va.w, jv, G2[3]);
            G2[4] = fmaf(vb.x, jv, G2[4]); G2[5] = fmaf(vb.y, jv, G2[5]);
            G2[6] = fmaf(vb.z, jv, G2[6]); G2[7] = fmaf(vb.w, jv, G2[7]);
        }
        #pragma unroll
        for (int u = 0; u < 8; ++u) { xc[u] = xn[u]; jc[u] = jn[u]; }
    }
    #pragma unroll
    for (int mi = 0; mi < 8; ++mi) {
        atomicAdd(&F1acc[(m0 + mi) * DESC + d], G1[mi]);
        atomicAdd(&F2acc[(m0 + mi) * DESC + d], G2[mi]);
    }
}

// final assembly — coef, force scatter, Es
__global__ __launch_bounds__(256) void k_final(const float* __restrict__ Rs,
                                               const float* __restrict__ aT,
                                               const float* __restrict__ S1,
                                               const float* __restrict__ EsAcc,
                                               const float* __restrict__ F1acc,
                                               const float* __restrict__ F2acc,
                                               float* __restrict__ out) {
    const int m = blockIdx.x;
    __shared__ float R[NATOMS * 3];
    __shared__ float FsL[NATOMS * 3];
    const int tid = threadIdx.x;
    if (tid < NATOMS * 3) {
        R[tid] = Rs[m * NATOMS * 3 + tid];
        FsL[tid] = 0.0f;
    }
    __syncthreads();
    if (tid < DESC) {
        int i, j;
        pair_ij(tid, i, j);
        const float dx = R[i * 3 + 0] - R[j * 3 + 0];
        const float dy = R[i * 3 + 1] - R[j * 3 + 1];
        const float dz = R[i * 3 + 2] - R[j * 3 + 2];
        const float r2 = dx * dx + dy * dy + dz * dz;
        const float rinv = 1.0f / sqrtf(r2);
        const float a = aT[tid * NM + m];  // q/r
        const float F1 = a * S1[m] - F1acc[m * DESC + tid];
        const float Fx = (F1 - F2acc[m * DESC + tid]) * STDC;
        const float coef = Fx * (rinv * rinv * rinv);
        atomicAdd(&FsL[j * 3 + 0], coef * dx);
        atomicAdd(&FsL[j * 3 + 1], coef * dy);
        atomicAdd(&FsL[j * 3 + 2], coef * dz);
        atomicAdd(&FsL[i * 3 + 0], -coef * dx);
        atomicAdd(&FsL[i * 3 + 1], -coef * dy);
        atomicAdd(&FsL[i * 3 + 2], -coef * dz);
    }
    __syncthreads();
    if (tid < NATOMS * 3) out[NM + m * NATOMS * 3 + tid] = FsL[tid];
    if (tid == 0) out[m] = CC + (EsAcc[m] / QS) * STDC;
}

extern "C" void kernel_launch(void* const* d_in, const int* in_sizes, int n_in,
                              void* d_out, int out_size, void* d_ws, size_t ws_size,
                              hipStream_t stream) {
    const float* Rs = (const float*)d_in[0];
    const float* xs_train = (const float*)d_in[1];
    const float* Jx = (const float*)d_in[2];
    float* out = (float*)d_out;
    float* ws = (float*)d_ws;

    float* F1acc = ws;                         // 26880
    float* F2acc = ws + 26880;                 // 26880
    float* EsAcc = ws + 53760;                 // 128
    float* S1 = ws + 53888;                    // 128   (zero block ends at 54016)
    float* aT = ws + 54016;                    // 224*128 = 28672
    float* asq = ws + 82688;                   // 128
    float4* bjq = (float4*)(ws + 82816);       // 112*4096 float4 = 1835008 floats
    float* w1Tm = ws + 1917824;                // 128*4096 = 524288
    float* w2Tm = ws + 2442112;                // 524288 -> total 2966400 floats (~11.9 MB)

    hipMemsetAsync(ws, 0, (size_t)54016 * sizeof(float), stream);

    k_prep<<<576, 256, 0, stream>>>(Rs, xs_train, Jx, bjq, aT, asq);
    k_pass1<<<dim3(NTRAIN / 256, NM / 8), 256, 0, stream>>>(bjq, aT, asq, w1Tm, w2Tm,
                                                            EsAcc, S1);
    k_pass2<<<dim3(NTRAIN / TC2, NM / 8), 256, 0, stream>>>(xs_train, Jx, w1Tm, w2Tm,
                                                            F1acc, F2acc);
    k_final<<<NM, 256, 0, stream>>>(Rs, aT, S1, EsAcc, F1acc, F2acc, out);
}